// Round 14
// baseline (854.005 us; speedup 1.0000x reference)
//
#include <hip/hip_runtime.h>
#include <hip/hip_bf16.h>
#include <cstddef>
#include <cstdint>

#define NNODES 500000
#define DIM    128
#define NSEG   8192
#define TSTEPS 6
#define SEGB   16      // segments per block

typedef __attribute__((ext_vector_type(8))) short bf16x8;
typedef __attribute__((ext_vector_type(4))) float f32x4;
typedef unsigned short ushort_t;

static __device__ inline ushort_t f2bf_u(float f) {
    __hip_bfloat16 h = __float2bfloat16(f);
    return *reinterpret_cast<ushort_t*>(&h);
}
static __device__ inline float bfu2f(ushort_t u) {
    union { unsigned i; float f; } c; c.i = ((unsigned)u) << 16; return c.f;
}

// ---------------------------------------------------------------------------
__global__ void seg_bounds_k(const int* __restrict__ batch, int* __restrict__ seg, int n) {
    int b = blockIdx.x * blockDim.x + threadIdx.x;
    if (b > NSEG) return;
    int lo = 0, hi = n;
    while (lo < hi) {
        int mid = (lo + hi) >> 1;
        if (batch[mid] < b) lo = mid + 1; else hi = mid;
    }
    seg[b] = lo;
}

// ---------------------------------------------------------------------------
__global__ __launch_bounds__(256) void wconv_k(
    const float* __restrict__ Wih, const float* __restrict__ Whh,
    __hip_bfloat16* __restrict__ wbuf)
{
    int idx = blockIdx.x * 256 + threadIdx.x;    // 512*384 exact
    int n = idx / 384, k = idx - n * 384;
    float v = (k < 256) ? Wih[n * 256 + k] : Whh[n * 128 + (k - 256)];
    wbuf[idx] = __float2bfloat16(v);
}

// ---------------------------------------------------------------------------
// Mega-kernel: block owns SEGB consecutive segments for ALL 6 steps.
// Per step: [A] MFMA gates (M=16 segs, K=384 from LDS Ash, W from L2);
// col-tiling gives each lane all 4 gates of its (seg,dim) pairs ->
// [B] LSTM fully in registers (c persists in VGPRs across steps) ->
// [C] flash attention, one 16-lane group per segment (solo owner, no merge).
// No cross-block dependencies exist; 3 __syncthreads per step.
// ---------------------------------------------------------------------------
__global__ __launch_bounds__(256) void set2set_mega_k(
    const float* __restrict__ x, ushort_t* __restrict__ xbf,
    const int* __restrict__ seg_arr, const __hip_bfloat16* __restrict__ wbuf,
    const float* __restrict__ bih, const float* __restrict__ bhh,
    float* __restrict__ qstar, int use_xbf)
{
    __shared__ ushort_t Ash[SEGB][392];   // bf16 A rows [q|r|h], pad 384->392 (2-way-free)
    __shared__ float    hsh[SEGB][128];   // fp32 h for attention dot
    __shared__ float    bsh[512];         // bih+bhh

    const int tid  = threadIdx.x;
    const int wv   = tid >> 6, lane = tid & 63;
    const int l16  = lane & 15, k8 = lane >> 4;
    const int s0   = blockIdx.x * SEGB;
    const int g    = tid >> 4;            // attention group = local segment 0..15
    const int segb = s0 + g;
    const int ns   = seg_arr[segb], ne = seg_arr[segb + 1];

    for (int i = tid; i < 512; i += 256) bsh[i] = bih[i] + bhh[i];

    // private LSTM cell state: lane owns segs s=4*k8+reg, dims d=32*wv+16*c2+l16
    float creg[8];
    #pragma unroll
    for (int i = 0; i < 8; ++i) creg[i] = 0.f;

    __syncthreads();

    for (int t = 0; t < TSTEPS; ++t) {
        // ===== phase A: gates MFMA (skipped at t=0: A(0)=0 -> gates = biases)
        f32x4 acc[4][2];
        if (t > 0) {
            #pragma unroll
            for (int gg2 = 0; gg2 < 4; ++gg2)
                #pragma unroll
                for (int c2 = 0; c2 < 2; ++c2)
                    acc[gg2][c2] = (f32x4){0.f, 0.f, 0.f, 0.f};
            #pragma unroll
            for (int ks = 0; ks < 12; ++ks) {
                bf16x8 af = *(const bf16x8*)&Ash[l16][ks * 32 + k8 * 8];
                #pragma unroll
                for (int gg2 = 0; gg2 < 4; ++gg2)
                    #pragma unroll
                    for (int c2 = 0; c2 < 2; ++c2) {
                        const int n = gg2 * 128 + wv * 32 + c2 * 16 + l16;
                        bf16x8 bf = *(const bf16x8*)((const ushort_t*)wbuf
                                     + (size_t)n * 384 + ks * 32 + k8 * 8);
                        acc[gg2][c2] = __builtin_amdgcn_mfma_f32_16x16x32_bf16(
                            af, bf, acc[gg2][c2], 0, 0, 0);
                    }
            }
        }
        __syncthreads();   // all waves' Ash reads done before LSTM rewrites h-cols

        // ===== phase B: LSTM in-register
        // D-frag map (m89/m91): col(n)=l16 handled via n above; row(seg)=4*k8+reg
        #pragma unroll
        for (int c2 = 0; c2 < 2; ++c2) {
            const int d = 32 * wv + 16 * c2 + l16;
            const float b0 = bsh[d], b1 = bsh[128 + d], b2 = bsh[256 + d], b3 = bsh[384 + d];
            #pragma unroll
            for (int reg = 0; reg < 4; ++reg) {
                const int s = 4 * k8 + reg;
                float gi = b0, gf = b1, gg = b2, go = b3;
                if (t > 0) {
                    gi += acc[0][c2][reg]; gf += acc[1][c2][reg];
                    gg += acc[2][c2][reg]; go += acc[3][c2][reg];
                }
                const float iv = 1.f / (1.f + expf(-gi));
                const float fv = 1.f / (1.f + expf(-gf));
                const float gv = tanhf(gg);
                const float ov = 1.f / (1.f + expf(-go));
                const float c  = fv * creg[reg * 2 + c2] + iv * gv;
                const float h  = ov * tanhf(c);
                creg[reg * 2 + c2] = c;
                hsh[s][d] = h;
                const ushort_t hb = f2bf_u(h);
                Ash[s][d] = hb;          // q-cols (q = h)
                Ash[s][256 + d] = hb;    // h-cols
                if (t == TSTEPS - 1) qstar[(size_t)(s0 + s) * 256 + d] = h;
            }
        }
        __syncthreads();   // hsh/Ash-h visible to attention

        // ===== phase C: flash attention, group g owns segment segb
        float hreg[8];
        #pragma unroll
        for (int i = 0; i < 8; ++i) hreg[i] = hsh[g][8 * l16 + i];

        float m = -INFINITY, den = 0.f;
        float racc[8] = {0.f, 0.f, 0.f, 0.f, 0.f, 0.f, 0.f, 0.f};
        const int read_bf = (use_xbf && t > 0) ? 1 : 0;

        if (ns < ne) {
            if (read_bf) {
                int4 v = *(const int4*)(xbf + (size_t)ns * DIM + 8 * l16);
                for (int j = ns; j < ne; ++j) {
                    int4 vn;
                    if (j + 1 < ne) vn = *(const int4*)(xbf + (size_t)(j + 1) * DIM + 8 * l16);
                    const ushort_t* u = (const ushort_t*)&v;
                    float xv[8];
                    #pragma unroll
                    for (int i = 0; i < 8; ++i) xv[i] = bfu2f(u[i]);
                    float sd = xv[0]*hreg[0] + xv[1]*hreg[1] + xv[2]*hreg[2] + xv[3]*hreg[3]
                             + xv[4]*hreg[4] + xv[5]*hreg[5] + xv[6]*hreg[6] + xv[7]*hreg[7];
                    sd += __shfl_xor(sd, 1); sd += __shfl_xor(sd, 2);
                    sd += __shfl_xor(sd, 4); sd += __shfl_xor(sd, 8);
                    const float mn = fmaxf(m, sd);
                    const float sc = expf(m - mn);
                    const float w  = expf(sd - mn);
                    den = den * sc + w;
                    #pragma unroll
                    for (int i = 0; i < 8; ++i) racc[i] = fmaf(racc[i], sc, w * xv[i]);
                    m = mn;
                    v = vn;
                }
            } else {
                const int do_wb = (use_xbf && t == 0) ? 1 : 0;
                const float4* xp = (const float4*)(x + (size_t)ns * DIM + 8 * l16);
                float4 va = xp[0], vb = xp[1];
                for (int j = ns; j < ne; ++j) {
                    float4 na, nb;
                    if (j + 1 < ne) {
                        const float4* xn = (const float4*)(x + (size_t)(j + 1) * DIM + 8 * l16);
                        na = xn[0]; nb = xn[1];
                    }
                    float xv[8] = {va.x, va.y, va.z, va.w, vb.x, vb.y, vb.z, vb.w};
                    if (do_wb) {
                        int4 pk;
                        unsigned* pu = (unsigned*)&pk;
                        pu[0] = (unsigned)f2bf_u(xv[0]) | ((unsigned)f2bf_u(xv[1]) << 16);
                        pu[1] = (unsigned)f2bf_u(xv[2]) | ((unsigned)f2bf_u(xv[3]) << 16);
                        pu[2] = (unsigned)f2bf_u(xv[4]) | ((unsigned)f2bf_u(xv[5]) << 16);
                        pu[3] = (unsigned)f2bf_u(xv[6]) | ((unsigned)f2bf_u(xv[7]) << 16);
                        *(int4*)(xbf + (size_t)j * DIM + 8 * l16) = pk;
                    }
                    float sd = xv[0]*hreg[0] + xv[1]*hreg[1] + xv[2]*hreg[2] + xv[3]*hreg[3]
                             + xv[4]*hreg[4] + xv[5]*hreg[5] + xv[6]*hreg[6] + xv[7]*hreg[7];
                    sd += __shfl_xor(sd, 1); sd += __shfl_xor(sd, 2);
                    sd += __shfl_xor(sd, 4); sd += __shfl_xor(sd, 8);
                    const float mn = fmaxf(m, sd);
                    const float sc = expf(m - mn);
                    const float w  = expf(sd - mn);
                    den = den * sc + w;
                    #pragma unroll
                    for (int i = 0; i < 8; ++i) racc[i] = fmaf(racc[i], sc, w * xv[i]);
                    m = mn;
                    va = na; vb = nb;
                }
            }
        }

        const float rden = 1.f / (den + 1e-16f);
        float rv[8];
        #pragma unroll
        for (int i = 0; i < 8; ++i) rv[i] = racc[i] * rden;
        {
            int4 pk;
            unsigned* pu = (unsigned*)&pk;
            #pragma unroll
            for (int i = 0; i < 4; ++i)
                pu[i] = (unsigned)f2bf_u(rv[2 * i]) | ((unsigned)f2bf_u(rv[2 * i + 1]) << 16);
            *(int4*)&Ash[g][128 + 8 * l16] = pk;   // r-cols of A
        }
        if (t == TSTEPS - 1) {
            *(float4*)(qstar + (size_t)segb * 256 + DIM + 8 * l16)
                = make_float4(rv[0], rv[1], rv[2], rv[3]);
            *(float4*)(qstar + (size_t)segb * 256 + DIM + 8 * l16 + 4)
                = make_float4(rv[4], rv[5], rv[6], rv[7]);
        }
        __syncthreads();   // Ash r-writes before next MFMA; hsh reads before next LSTM
    }
}

// ---------------------------------------------------------------------------
extern "C" void kernel_launch(void* const* d_in, const int* in_sizes, int n_in,
                              void* d_out, int out_size, void* d_ws, size_t ws_size,
                              hipStream_t stream) {
    const float* x     = (const float*)d_in[0];
    const int*   batch = (const int*)d_in[1];
    const float* Wih   = (const float*)d_in[2];
    const float* Whh   = (const float*)d_in[3];
    const float* bih   = (const float*)d_in[4];
    const float* bhh   = (const float*)d_in[5];
    float* out = (float*)d_out;

    // workspace: wbuf (512*384 bf16) | seg (8193 int) | xbf (500000*128 bf16)
    __hip_bfloat16* wbuf = (__hip_bfloat16*)d_ws;
    int* seg = (int*)(wbuf + (size_t)512 * 384);
    size_t fixed_bytes = (size_t)((char*)(seg + NSEG + 1) - (char*)d_ws);
    size_t xbf_off = (fixed_bytes + 15) & ~(size_t)15;
    ushort_t* xbf = (ushort_t*)((char*)d_ws + xbf_off);
    size_t need = xbf_off + (size_t)NNODES * DIM * sizeof(ushort_t);
    const int use_xbf = (ws_size >= need) ? 1 : 0;

    seg_bounds_k<<<(NSEG + 256) / 256, 256, 0, stream>>>(batch, seg, NNODES);
    wconv_k<<<(512 * 384) / 256, 256, 0, stream>>>(Wih, Whh, wbuf);

    set2set_mega_k<<<NSEG / SEGB, 256, 0, stream>>>(x, xbf, seg, wbuf,
                                                    bih, bhh, out, use_xbf);
}

// Round 15
// 373.197 us; speedup vs baseline: 2.2883x; 2.2883x over previous
//
#include <hip/hip_runtime.h>
#include <hip/hip_bf16.h>
#include <cstddef>
#include <cstdint>

#define NNODES 500000
#define DIM    128
#define NSEG   8192
#define TSTEPS 6

typedef __attribute__((ext_vector_type(8))) short bf16x8;
typedef __attribute__((ext_vector_type(4))) float f32x4;
typedef unsigned short ushort_t;

static __device__ inline ushort_t f2bf_u(float f) {
    __hip_bfloat16 h = __float2bfloat16(f);
    return *reinterpret_cast<ushort_t*>(&h);
}
static __device__ inline float bfu2f(ushort_t u) {
    union { unsigned i; float f; } c; c.i = ((unsigned)u) << 16; return c.f;
}

// ---------------------------------------------------------------------------
__global__ void seg_bounds_k(const int* __restrict__ batch, int* __restrict__ seg, int n) {
    int b = blockIdx.x * blockDim.x + threadIdx.x;
    if (b > NSEG) return;
    int lo = 0, hi = n;
    while (lo < hi) {
        int mid = (lo + hi) >> 1;
        if (batch[mid] < b) lo = mid + 1; else hi = mid;
    }
    seg[b] = lo;
}

// ---------------------------------------------------------------------------
__global__ __launch_bounds__(256) void wconv_k(
    const float* __restrict__ Wih, const float* __restrict__ Whh,
    __hip_bfloat16* __restrict__ wbuf)
{
    int idx = blockIdx.x * 256 + threadIdx.x;    // 512*384 exact
    int n = idx / 384, k = idx - n * 384;
    float v = (k < 256) ? Wih[n * 256 + k] : Whh[n * 128 + (k - 256)];
    wbuf[idx] = __float2bfloat16(v);
}

// ---------------------------------------------------------------------------
// gates = Abf @ Wbf^T  (fp32 accumulate). A=[8192][384] bf16 = [q|r|h],
// W=[512][384] bf16. MFMA 16x16x32, BM=128 BN=64 BK=64, 4 waves (2x2).
// ---------------------------------------------------------------------------
__global__ __launch_bounds__(256) void gemm_mfma_k(
    const __hip_bfloat16* __restrict__ abuf,
    const __hip_bfloat16* __restrict__ wbuf,
    float* __restrict__ gates)
{
    __shared__ char As[128 * 128];
    __shared__ char Bs[64 * 128];
    const int tid  = threadIdx.x;
    const int lane = tid & 63, wave = tid >> 6;
    const int wrow = (wave >> 1) * 64;
    const int wcol = (wave & 1) * 32;
    const int m0 = blockIdx.y * 128;
    const int n0 = blockIdx.x * 64;

    const int ar  = tid >> 1;
    const int acb = (tid & 1) * 64;
    const int br  = tid >> 2;
    const int bcb = (tid & 3) * 32;

    const char* aP = (const char*)(abuf + (size_t)(m0 + ar) * 384) + acb;
    const char* bP = (const char*)(wbuf + (size_t)(n0 + br) * 384) + bcb;

    f32x4 acc[4][2] = {};

    int4 ra[4]; int4 rb2[2];
    #pragma unroll
    for (int c = 0; c < 4; ++c) ra[c]  = *(const int4*)(aP + c * 16);
    #pragma unroll
    for (int c = 0; c < 2; ++c) rb2[c] = *(const int4*)(bP + c * 16);

    char* asw = As + ar * 128;
    char* bsw = Bs + br * 128;
    const int amask = (ar & 7) << 4;
    const int bmask = (br & 7) << 4;

    for (int s = 0; s < 6; ++s) {
        __syncthreads();
        #pragma unroll
        for (int c = 0; c < 4; ++c)
            *(int4*)(asw + ((acb + c * 16) ^ amask)) = ra[c];
        #pragma unroll
        for (int c = 0; c < 2; ++c)
            *(int4*)(bsw + ((bcb + c * 16) ^ bmask)) = rb2[c];
        __syncthreads();

        if (s < 5) {
            const char* aN = aP + (size_t)(s + 1) * 128;
            const char* bN = bP + (size_t)(s + 1) * 128;
            #pragma unroll
            for (int c = 0; c < 4; ++c) ra[c]  = *(const int4*)(aN + c * 16);
            #pragma unroll
            for (int c = 0; c < 2; ++c) rb2[c] = *(const int4*)(bN + c * 16);
        }

        #pragma unroll
        for (int ks = 0; ks < 2; ++ks) {
            const int kb = ks * 64 + ((lane >> 4) << 4);
            bf16x8 af[4], bfr[2];
            #pragma unroll
            for (int rbk = 0; rbk < 4; ++rbk) {
                int r = wrow + rbk * 16 + (lane & 15);
                af[rbk] = *(const bf16x8*)(As + r * 128 + (kb ^ ((r & 7) << 4)));
            }
            #pragma unroll
            for (int cb = 0; cb < 2; ++cb) {
                int n = wcol + cb * 16 + (lane & 15);
                bfr[cb] = *(const bf16x8*)(Bs + n * 128 + (kb ^ ((n & 7) << 4)));
            }
            #pragma unroll
            for (int rbk = 0; rbk < 4; ++rbk)
                #pragma unroll
                for (int cb = 0; cb < 2; ++cb)
                    acc[rbk][cb] = __builtin_amdgcn_mfma_f32_16x16x32_bf16(
                        af[rbk], bfr[cb], acc[rbk][cb], 0, 0, 0);
        }
    }

    const int rowb = (lane >> 4) << 2;
    const int coll = lane & 15;
    #pragma unroll
    for (int rbk = 0; rbk < 4; ++rbk)
        #pragma unroll
        for (int cb = 0; cb < 2; ++cb) {
            int row = m0 + wrow + rbk * 16 + rowb;
            int col = n0 + wcol + cb * 16 + coll;
            float* gp = gates + (size_t)row * 512 + col;
            #pragma unroll
            for (int reg = 0; reg < 4; ++reg)
                gp[(size_t)reg * 512] = acc[rbk][cb][reg];
        }
}

#define REDUCE16(s) do { \
    s += __shfl_xor(s, 1); s += __shfl_xor(s, 2); \
    s += __shfl_xor(s, 4); s += __shfl_xor(s, 8); } while (0)

// ---------------------------------------------------------------------------
// Fused LSTM + flash attention, 4-row-batched. Block = segment b (128 thr).
// LSTM prologue (thread=dim) -> h in LDS. 8 groups of 16 lanes stream rows
// (group g: rows ns+g, ns+g+8, ...), 4 rows per iteration: 4 loads issued
// upfront (4x MLP), 4 independent dot/shfl reduces (ILP), ONE online-softmax
// rescale per 4 rows (serial chain cut 4x, 5 exp per batch vs 8).
// Tail rows: clamped address + sd=-inf => w=0 (exact). LDS merge at end.
// ---------------------------------------------------------------------------
__global__ __launch_bounds__(128) void attn_lstm_k(
    const float* __restrict__ x, ushort_t* __restrict__ xbf,
    const int* __restrict__ seg, const float* __restrict__ gates,
    const float* __restrict__ bih, const float* __restrict__ bhh,
    float* __restrict__ cbuf, float* __restrict__ qstar,
    __hip_bfloat16* __restrict__ abuf,
    int t0, int read_bf, int write_bf)
{
    const int tid  = threadIdx.x;
    const int wv   = tid >> 6, lane = tid & 63;
    const int b    = blockIdx.x;
    const int l16  = lane & 15;
    const int ggrp = (wv << 2) | (lane >> 4);   // 0..7

    __shared__ float hsh[128];
    __shared__ float gm[8], gden[8];
    __shared__ float racc_s[8][128];

    // ---- LSTM prologue: dim d = tid
    {
        const int d = tid;
        float gi, gf, gg, go;
        if (t0) {
            gi = bih[d]       + bhh[d];
            gf = bih[128 + d] + bhh[128 + d];
            gg = bih[256 + d] + bhh[256 + d];
            go = bih[384 + d] + bhh[384 + d];
        } else {
            const float* g = gates + (size_t)b * 512;
            gi = g[d]       + bih[d]       + bhh[d];
            gf = g[128 + d] + bih[128 + d] + bhh[128 + d];
            gg = g[256 + d] + bih[256 + d] + bhh[256 + d];
            go = g[384 + d] + bih[384 + d] + bhh[384 + d];
        }
        float iv = 1.f / (1.f + expf(-gi));
        float fv = 1.f / (1.f + expf(-gf));
        float gv = tanhf(gg);
        float ov = 1.f / (1.f + expf(-go));
        float cp = t0 ? 0.f : cbuf[(size_t)b * 128 + d];
        float c  = fv * cp + iv * gv;
        float h  = ov * tanhf(c);
        cbuf[(size_t)b * 128 + d] = c;
        qstar[(size_t)b * 256 + d] = h;
        __hip_bfloat16 hb = __float2bfloat16(h);
        abuf[(size_t)b * 384 + d] = hb;
        abuf[(size_t)b * 384 + 256 + d] = hb;
        hsh[d] = h;
    }
    __syncthreads();

    const int ns = seg[b], ne = seg[b + 1];
    if (ns >= ne) {
        qstar[(size_t)b * 256 + DIM + tid] = 0.f;
        abuf[(size_t)b * 384 + 128 + tid] = __float2bfloat16(0.f);
        return;
    }

    // lane's 8 dims: [8*l16, 8*l16+8)
    float hreg[8];
    #pragma unroll
    for (int i = 0; i < 8; ++i) hreg[i] = hsh[8 * l16 + i];

    float m = -INFINITY, den = 0.f;
    float racc[8] = {};

    if (read_bf) {
        for (int j = ns + ggrp; j < ne; j += 32) {
            const int j1 = j + 8, j2 = j + 16, j3 = j + 24;
            const size_t off = 8 * l16;
            int4 v0 = *(const int4*)(xbf + (size_t)j * DIM + off);
            int4 v1 = *(const int4*)(xbf + (size_t)(j1 < ne ? j1 : j) * DIM + off);
            int4 v2 = *(const int4*)(xbf + (size_t)(j2 < ne ? j2 : j) * DIM + off);
            int4 v3 = *(const int4*)(xbf + (size_t)(j3 < ne ? j3 : j) * DIM + off);
            float x0[8], x1[8], x2[8], x3[8];
            {
                const ushort_t* u0 = (const ushort_t*)&v0;
                const ushort_t* u1 = (const ushort_t*)&v1;
                const ushort_t* u2 = (const ushort_t*)&v2;
                const ushort_t* u3 = (const ushort_t*)&v3;
                #pragma unroll
                for (int i = 0; i < 8; ++i) {
                    x0[i] = bfu2f(u0[i]); x1[i] = bfu2f(u1[i]);
                    x2[i] = bfu2f(u2[i]); x3[i] = bfu2f(u3[i]);
                }
            }
            float s0 = 0.f, s1 = 0.f, s2 = 0.f, s3 = 0.f;
            #pragma unroll
            for (int i = 0; i < 8; ++i) {
                s0 = fmaf(x0[i], hreg[i], s0);
                s1 = fmaf(x1[i], hreg[i], s1);
                s2 = fmaf(x2[i], hreg[i], s2);
                s3 = fmaf(x3[i], hreg[i], s3);
            }
            REDUCE16(s0); REDUCE16(s1); REDUCE16(s2); REDUCE16(s3);
            if (j1 >= ne) s1 = -INFINITY;
            if (j2 >= ne) s2 = -INFINITY;
            if (j3 >= ne) s3 = -INFINITY;
            const float mn = fmaxf(fmaxf(m, s0), fmaxf(fmaxf(s1, s2), s3));
            const float sc = expf(m - mn);
            const float w0 = expf(s0 - mn), w1 = expf(s1 - mn);
            const float w2 = expf(s2 - mn), w3 = expf(s3 - mn);
            den = den * sc + ((w0 + w1) + (w2 + w3));
            #pragma unroll
            for (int i = 0; i < 8; ++i) {
                float tacc = w0 * x0[i];
                tacc = fmaf(w1, x1[i], tacc);
                tacc = fmaf(w2, x2[i], tacc);
                tacc = fmaf(w3, x3[i], tacc);
                racc[i] = fmaf(racc[i], sc, tacc);
            }
            m = mn;
        }
    } else {
        for (int j = ns + ggrp; j < ne; j += 32) {
            const int jr[4] = {j, j + 8, j + 16, j + 24};
            float xv[4][8];
            #pragma unroll
            for (int r4 = 0; r4 < 4; ++r4) {
                const int ja = (jr[r4] < ne) ? jr[r4] : j;
                const float4* xp = (const float4*)(x + (size_t)ja * DIM + 8 * l16);
                float4 a = xp[0], bq = xp[1];
                xv[r4][0] = a.x;  xv[r4][1] = a.y;  xv[r4][2] = a.z;  xv[r4][3] = a.w;
                xv[r4][4] = bq.x; xv[r4][5] = bq.y; xv[r4][6] = bq.z; xv[r4][7] = bq.w;
            }
            if (write_bf) {
                #pragma unroll
                for (int r4 = 0; r4 < 4; ++r4) {
                    if (r4 == 0 || jr[r4] < ne) {
                        int4 pk;
                        unsigned* pu = (unsigned*)&pk;
                        #pragma unroll
                        for (int i = 0; i < 4; ++i)
                            pu[i] = (unsigned)f2bf_u(xv[r4][2 * i])
                                  | ((unsigned)f2bf_u(xv[r4][2 * i + 1]) << 16);
                        *(int4*)(xbf + (size_t)jr[r4] * DIM + 8 * l16) = pk;
                    }
                }
            }
            float s0 = 0.f, s1 = 0.f, s2 = 0.f, s3 = 0.f;
            #pragma unroll
            for (int i = 0; i < 8; ++i) {
                s0 = fmaf(xv[0][i], hreg[i], s0);
                s1 = fmaf(xv[1][i], hreg[i], s1);
                s2 = fmaf(xv[2][i], hreg[i], s2);
                s3 = fmaf(xv[3][i], hreg[i], s3);
            }
            REDUCE16(s0); REDUCE16(s1); REDUCE16(s2); REDUCE16(s3);
            if (jr[1] >= ne) s1 = -INFINITY;
            if (jr[2] >= ne) s2 = -INFINITY;
            if (jr[3] >= ne) s3 = -INFINITY;
            const float mn = fmaxf(fmaxf(m, s0), fmaxf(fmaxf(s1, s2), s3));
            const float sc = expf(m - mn);
            const float w0 = expf(s0 - mn), w1 = expf(s1 - mn);
            const float w2 = expf(s2 - mn), w3 = expf(s3 - mn);
            den = den * sc + ((w0 + w1) + (w2 + w3));
            #pragma unroll
            for (int i = 0; i < 8; ++i) {
                float tacc = w0 * xv[0][i];
                tacc = fmaf(w1, xv[1][i], tacc);
                tacc = fmaf(w2, xv[2][i], tacc);
                tacc = fmaf(w3, xv[3][i], tacc);
                racc[i] = fmaf(racc[i], sc, tacc);
            }
            m = mn;
        }
    }

    // ---- merge 8 group states
    if (l16 == 0) { gm[ggrp] = m; gden[ggrp] = den; }
    *(float4*)&racc_s[ggrp][8 * l16]     = make_float4(racc[0], racc[1], racc[2], racc[3]);
    *(float4*)&racc_s[ggrp][8 * l16 + 4] = make_float4(racc[4], racc[5], racc[6], racc[7]);
    __syncthreads();

    {
        float mM = gm[0];
        #pragma unroll
        for (int g = 1; g < 8; ++g) mM = fmaxf(mM, gm[g]);
        float dtot = 0.f, rtot = 0.f;
        #pragma unroll
        for (int g = 0; g < 8; ++g) {
            const float k = expf(gm[g] - mM);   // -inf group -> 0
            dtot = fmaf(k, gden[g], dtot);
            rtot = fmaf(k, racc_s[g][tid], rtot);
        }
        const float rv = rtot / (dtot + 1e-16f);
        qstar[(size_t)b * 256 + DIM + tid] = rv;
        abuf[(size_t)b * 384 + 128 + tid] = __float2bfloat16(rv);
    }
}

// ---------------------------------------------------------------------------
extern "C" void kernel_launch(void* const* d_in, const int* in_sizes, int n_in,
                              void* d_out, int out_size, void* d_ws, size_t ws_size,
                              hipStream_t stream) {
    const float* x     = (const float*)d_in[0];
    const int*   batch = (const int*)d_in[1];
    const float* Wih   = (const float*)d_in[2];
    const float* Whh   = (const float*)d_in[3];
    const float* bih   = (const float*)d_in[4];
    const float* bhh   = (const float*)d_in[5];
    float* out = (float*)d_out;

    // workspace layout
    float* cbuf  = (float*)d_ws;                            // 8192*128 f32
    float* gates = cbuf + (size_t)NSEG * DIM;               // 8192*512 f32
    __hip_bfloat16* abuf = (__hip_bfloat16*)(gates + (size_t)NSEG * 512);  // 8192*384
    __hip_bfloat16* wbuf = abuf + (size_t)NSEG * 384;       // 512*384
    int* seg = (int*)(wbuf + (size_t)512 * 384);
    size_t fixed_bytes = (size_t)((char*)(seg + NSEG + 1) - (char*)d_ws);
    size_t xbf_off = (fixed_bytes + 15) & ~(size_t)15;
    ushort_t* xbf = (ushort_t*)((char*)d_ws + xbf_off);
    size_t need = xbf_off + (size_t)NNODES * DIM * sizeof(ushort_t);
    const int use_xbf = (ws_size >= need) ? 1 : 0;

    seg_bounds_k<<<(NSEG + 256) / 256, 256, 0, stream>>>(batch, seg, NNODES);
    wconv_k<<<(512 * 384) / 256, 256, 0, stream>>>(Wih, Whh, wbuf);

    dim3 ggrid(512 / 64, NSEG / 128);   // (8, 64)
    for (int t = 0; t < TSTEPS; ++t) {
        if (t > 0)
            gemm_mfma_k<<<ggrid, 256, 0, stream>>>(abuf, wbuf, gates);
        const int read_bf  = (use_xbf && t > 0) ? 1 : 0;
        const int write_bf = (use_xbf && t == 0) ? 1 : 0;
        attn_lstm_k<<<NSEG, 128, 0, stream>>>(x, xbf, seg, gates, bih, bhh,
                                              cbuf, out, abuf,
                                              (t == 0) ? 1 : 0, read_bf, write_bf);
    }
}